// Round 10
// baseline (512.745 us; speedup 1.0000x reference)
//
#include <hip/hip_runtime.h>
#include <hip/hip_bf16.h>

// Transformer forward. All-bf16 MFMA GEMMs (pre-transposed bf16 weights,
// bf16 activation shadows), 128x64 GEMM tiles with global_load_lds + XOR-swizzle
// + 2-phase double buffer. Residual+LayerNorm fused into GEMM epilogues.
// B=8 T=512 A=512 C=8 D=256 H=8 dh=32 FF=1024 DEC_FF=512 L=3
constexpr int CB = 8;
constexpr int CT = 512;
constexpr int CA = 512;
constexpr int CC = 8;
constexpr int CD = 256;
constexpr float NEGV = -1.0e9f;

typedef __attribute__((ext_vector_type(8))) short bf16x8;
typedef __attribute__((ext_vector_type(4))) float f32x4;

__device__ inline short f2bf(float f) {
  uint32_t u = __float_as_uint(f);
  uint32_t r = (u + 0x7FFFu + ((u >> 16) & 1u)) >> 16;
  return (short)r;
}

// ---------------- masks ----------------
__global__ void mask_prep_kernel(const int* __restrict__ tasks,
                                 const int* __restrict__ indices,
                                 int* __restrict__ asgn, int* __restrict__ fullm,
                                 int* __restrict__ padm) {
  int i = blockIdx.x * blockDim.x + threadIdx.x;
  if (i >= CB * CT) return;
  asgn[i] = 0;
  const int* tp = tasks + i * 4;
  padm[i] = (tp[0] == -1) && (tp[1] == -1) && (tp[2] == -1) && (tp[3] == -1);
  const int* ip = indices + i * CC;
  int full = 1;
#pragma unroll
  for (int c = 0; c < CC; ++c) full &= (ip[c] != -1);
  fullm[i] = full;
}

__global__ void mask_assign_kernel(const int* __restrict__ indices, int* __restrict__ asgn) {
  int i = blockIdx.x * blockDim.x + threadIdx.x;
  if (i >= CB * CA * CC) return;
  int b = i / (CA * CC);
  int idx = indices[i];
  if (idx >= 0) asgn[b * CT + idx] = 1;   // benign race: same value
}

// ---------------- weight pre-transpose: f32 [K][N] -> bf16 [N][K] ----------------
struct TDesc { const float* src; short* dst; int K; int N; int tbase; };
struct TArgs { TDesc d[46]; int nd; };

__global__ __launch_bounds__(256) void trans_kernel(TArgs a) {
  __shared__ short Ts[64][72];
  const int bid = blockIdx.x;
  int w = 0;
#pragma unroll 1
  for (int i = 1; i < a.nd; ++i)
    if (a.d[i].tbase <= bid) w = i;
  const TDesc de = a.d[w];
  const int ti = bid - de.tbase;
  const int ntn = de.N >> 6;
  const int n0 = (ti % ntn) * 64, k0 = (ti / ntn) * 64;
  const int t = threadIdx.x;
  const int kk = t >> 4, c4 = (t & 15) * 4;
#pragma unroll
  for (int r = 0; r < 4; ++r) {
    float4 v = *(const float4*)(de.src + (size_t)(k0 + kk + r * 16) * de.N + n0 + c4);
    Ts[c4 + 0][kk + r * 16] = f2bf(v.x);
    Ts[c4 + 1][kk + r * 16] = f2bf(v.y);
    Ts[c4 + 2][kk + r * 16] = f2bf(v.z);
    Ts[c4 + 3][kk + r * 16] = f2bf(v.w);
  }
  __syncthreads();
  const int n = t >> 3, k8 = (t & 7) * 8;
#pragma unroll
  for (int r = 0; r < 2; ++r)
    *(bf16x8*)(de.dst + (size_t)(n0 + n + r * 32) * de.K + k0 + k8) =
        *(bf16x8*)&Ts[n + r * 32][k8];
}

// ---------------- embedding gather+sum -> bf16 (both tables, one dispatch) ----------------
__global__ void embed2_kernel(const int* __restrict__ tasks, const int* __restrict__ agents,
                              const float* __restrict__ tab_t, const float* __restrict__ tab_a,
                              short* __restrict__ out) {
  int row = blockIdx.x;   // 0..8191
  int lane = threadIdx.x;
  const int* tp;
  const float* table;
  int nf;
  short* dst;
  if (row < 4096) {
    tp = tasks + row * 4; table = tab_t; nf = 4; dst = out + (size_t)row * CD;
  } else {
    int r = row - 4096;
    tp = agents + r * 2; table = tab_a; nf = 2; dst = out + 1048576 + (size_t)r * CD;
  }
  float4 acc = make_float4(0.f, 0.f, 0.f, 0.f);
  for (int f = 0; f < nf; ++f) {
    int t = 1 + tp[f];
    float4 v = *(const float4*)(table + ((size_t)f * 33 + t) * CD + lane * 4);
    acc.x += v.x; acc.y += v.y; acc.z += v.z; acc.w += v.w;
  }
  short4 o;
  o.x = f2bf(acc.x); o.y = f2bf(acc.y); o.z = f2bf(acc.z); o.w = f2bf(acc.w);
  *(short4*)(dst + lane * 4) = o;
}

// ---------------- bf16 MFMA GEMM body: A bf16 [M][K], B bf16 [N][K] ----------------
// Tile 128x64, BK=64, 256 threads = 4 waves; wave w owns rows [w*32, w*32+32) x 64 cols.
// LDS linear + XOR swizzle (chunk c of row r at physical c^(r&7)); global_load_lds 16B,
// pre-swizzled global src; 2-phase double buffer. CMODE: 0 f32 C, 1 bf16 C, 2 both.
template <int CMODE, bool BIAS, bool RELU>
__device__ __forceinline__ void gemm_body(
    const short* __restrict__ Ab, const short* __restrict__ Bb,
    const float* __restrict__ bias, float* __restrict__ Cf, short* __restrict__ Cbf,
    int Ndim, int Kdim, int bm, int bn) {
  __shared__ __align__(16) short As[2][128 * 64];
  __shared__ __align__(16) short Bs[2][64 * 64];
  const int t = threadIdx.x;
  const int lane = t & 63, wave = t >> 6;
  const int wm = wave * 32;
  const int fr = lane & 15, fs = lane >> 4;
  const int fr7 = fr & 7;

  const int srow = t >> 3;                      // 0..31
  const int lc = (t & 7) ^ (srow & 7);          // logical chunk fetched by this thread
  const short* Asrc = Ab + (size_t)(bm + srow) * Kdim + lc * 8;
  const short* Bsrc = Bb + (size_t)(bn + srow) * Kdim + lc * 8;

  f32x4 acc[2][4] = {};

  auto stage = [&](int buf, int k0) {
#pragma unroll
    for (int r = 0; r < 4; ++r)
      __builtin_amdgcn_global_load_lds(
          (const __attribute__((address_space(1))) void*)(Asrc + (size_t)(r * 32) * Kdim + k0),
          (__attribute__((address_space(3))) void*)(&As[buf][r * 2048 + wave * 512]),
          16, 0, 0);
#pragma unroll
    for (int r = 0; r < 2; ++r)
      __builtin_amdgcn_global_load_lds(
          (const __attribute__((address_space(1))) void*)(Bsrc + (size_t)(r * 32) * Kdim + k0),
          (__attribute__((address_space(3))) void*)(&Bs[buf][r * 2048 + wave * 512]),
          16, 0, 0);
  };

  stage(0, 0);
  __syncthreads();
  int buf = 0;
#pragma unroll 1
  for (int k0 = 0; k0 < Kdim; k0 += 64) {
    if (k0 + 64 < Kdim) stage(buf ^ 1, k0 + 64);
    const short* A0 = &As[buf][(wm + fr) * 64];
    const short* A1 = &As[buf][(wm + 16 + fr) * 64];
    const short* B0 = &Bs[buf][fr * 64];
    const short* B1 = &Bs[buf][(16 + fr) * 64];
    const short* B2 = &Bs[buf][(32 + fr) * 64];
    const short* B3 = &Bs[buf][(48 + fr) * 64];
#pragma unroll
    for (int kk = 0; kk < 2; ++kk) {
      const int co = (((kk * 4) + fs) ^ fr7) * 8;
      bf16x8 a0 = *(bf16x8*)(A0 + co);
      bf16x8 a1 = *(bf16x8*)(A1 + co);
      bf16x8 bf0 = *(bf16x8*)(B0 + co);
      bf16x8 bf1 = *(bf16x8*)(B1 + co);
      bf16x8 bf2 = *(bf16x8*)(B2 + co);
      bf16x8 bf3 = *(bf16x8*)(B3 + co);
      acc[0][0] = __builtin_amdgcn_mfma_f32_16x16x32_bf16(a0, bf0, acc[0][0], 0, 0, 0);
      acc[0][1] = __builtin_amdgcn_mfma_f32_16x16x32_bf16(a0, bf1, acc[0][1], 0, 0, 0);
      acc[0][2] = __builtin_amdgcn_mfma_f32_16x16x32_bf16(a0, bf2, acc[0][2], 0, 0, 0);
      acc[0][3] = __builtin_amdgcn_mfma_f32_16x16x32_bf16(a0, bf3, acc[0][3], 0, 0, 0);
      acc[1][0] = __builtin_amdgcn_mfma_f32_16x16x32_bf16(a1, bf0, acc[1][0], 0, 0, 0);
      acc[1][1] = __builtin_amdgcn_mfma_f32_16x16x32_bf16(a1, bf1, acc[1][1], 0, 0, 0);
      acc[1][2] = __builtin_amdgcn_mfma_f32_16x16x32_bf16(a1, bf2, acc[1][2], 0, 0, 0);
      acc[1][3] = __builtin_amdgcn_mfma_f32_16x16x32_bf16(a1, bf3, acc[1][3], 0, 0, 0);
    }
    __syncthreads();
    buf ^= 1;
  }

#pragma unroll
  for (int fi = 0; fi < 2; ++fi)
#pragma unroll
    for (int fj = 0; fj < 4; ++fj) {
      int row0 = bm + wm + fi * 16 + fs * 4;
      int col = bn + fj * 16 + fr;
      float bv = BIAS ? bias[col] : 0.0f;
#pragma unroll
      for (int r = 0; r < 4; ++r) {
        float v = acc[fi][fj][r] + bv;
        if (RELU) v = fmaxf(v, 0.0f);
        if (CMODE == 0 || CMODE == 2) Cf[(size_t)(row0 + r) * Ndim + col] = v;
        if (CMODE == 1 || CMODE == 2) Cbf[(size_t)(row0 + r) * Ndim + col] = f2bf(v);
      }
    }
}

// generic multi-GEMM: blockIdx.z selects pointer set
struct GArgs {
  const short* A[8];
  const short* Bm[8];
  const float* bias[8];
  float* Cf[8];
  short* Cb[8];
  int Ndim, Kdim;
};

template <int CMODE, bool BIAS, bool RELU>
__global__ __launch_bounds__(256) void mgemm_kernel(GArgs ga) {
  int z = blockIdx.z;
  gemm_body<CMODE, BIAS, RELU>(ga.A[z], ga.Bm[z], ga.bias[z], ga.Cf[z], ga.Cb[z],
                               ga.Ndim, ga.Kdim, blockIdx.x * 128, blockIdx.y * 64);
}

// ---------------- GEMM + residual + LayerNorm fused (N = 256 full row per block) ----------------
// Tile 64x256, BK=64, 256 threads = 4 waves; wave w owns rows [w*16, w*16+16) x all 256 cols.
// x (f32 residual stream) updated in place; bf16 shadow xb written. LN over the 256 cols.
struct LArgs {
  const short* A[4];
  const short* Bm[4];     // [256][K] bf16
  const float* bias[4];
  float* x[4];            // f32 [M][256] in/out
  short* xb[4];           // bf16 [M][256] out
  const float* g[4];
  const float* be[4];
  int Kdim;
};

template <bool BIAS>
__global__ __launch_bounds__(256) void mgemmln_kernel(LArgs la) {
  const int z = blockIdx.z;
  const short* __restrict__ Ab = la.A[z];
  const short* __restrict__ Bb = la.Bm[z];
  const int Kdim = la.Kdim;
  const int bm = blockIdx.x * 64;
  __shared__ __align__(16) short As[2][64 * 64];
  __shared__ __align__(16) short Bs[2][256 * 64];
  const int t = threadIdx.x;
  const int lane = t & 63, wave = t >> 6;
  const int fr = lane & 15, fs = lane >> 4;
  const int fr7 = fr & 7;

  const int srow = t >> 3;
  const int lc = (t & 7) ^ (srow & 7);
  const short* Asrc = Ab + (size_t)(bm + srow) * Kdim + lc * 8;
  const short* Bsrc = Bb + (size_t)srow * Kdim + lc * 8;   // B rows 0..255

  f32x4 acc[16] = {};

  auto stage = [&](int buf, int k0) {
#pragma unroll
    for (int r = 0; r < 2; ++r)
      __builtin_amdgcn_global_load_lds(
          (const __attribute__((address_space(1))) void*)(Asrc + (size_t)(r * 32) * Kdim + k0),
          (__attribute__((address_space(3))) void*)(&As[buf][r * 2048 + wave * 512]),
          16, 0, 0);
#pragma unroll
    for (int r = 0; r < 8; ++r)
      __builtin_amdgcn_global_load_lds(
          (const __attribute__((address_space(1))) void*)(Bsrc + (size_t)(r * 32) * Kdim + k0),
          (__attribute__((address_space(3))) void*)(&Bs[buf][r * 2048 + wave * 512]),
          16, 0, 0);
  };

  stage(0, 0);
  __syncthreads();
  int buf = 0;
#pragma unroll 1
  for (int k0 = 0; k0 < Kdim; k0 += 64) {
    if (k0 + 64 < Kdim) stage(buf ^ 1, k0 + 64);
    const short* A0 = &As[buf][(wave * 16 + fr) * 64];
#pragma unroll
    for (int kk = 0; kk < 2; ++kk) {
      const int co = (((kk * 4) + fs) ^ fr7) * 8;
      bf16x8 a0 = *(bf16x8*)(A0 + co);
#pragma unroll
      for (int fj = 0; fj < 16; ++fj) {
        bf16x8 bfj = *(bf16x8*)(&Bs[buf][(fj * 16 + fr) * 64] + co);
        acc[fj] = __builtin_amdgcn_mfma_f32_16x16x32_bf16(a0, bfj, acc[fj], 0, 0, 0);
      }
    }
    __syncthreads();
    buf ^= 1;
  }

  // epilogue: v = acc (+bias) + x; LN across the 256 cols of each row.
  float* __restrict__ xf = la.x[z];
  short* __restrict__ xb = la.xb[z];
  const float* __restrict__ gp = la.g[z];
  const float* __restrict__ bep = la.be[z];
  const int rbase = bm + wave * 16 + fs * 4;   // rows rbase..rbase+3
#pragma unroll
  for (int fj = 0; fj < 16; ++fj) {
    int col = fj * 16 + fr;
    float bv = BIAS ? la.bias[z][col] : 0.0f;
#pragma unroll
    for (int r = 0; r < 4; ++r)
      acc[fj][r] += bv + xf[(size_t)(rbase + r) * 256 + col];
  }
  float s[4] = {0.f, 0.f, 0.f, 0.f}, s2[4] = {0.f, 0.f, 0.f, 0.f};
#pragma unroll
  for (int fj = 0; fj < 16; ++fj)
#pragma unroll
    for (int r = 0; r < 4; ++r) {
      float u = acc[fj][r];
      s[r] += u;
      s2[r] += u * u;
    }
#pragma unroll
  for (int off = 8; off >= 1; off >>= 1)
#pragma unroll
    for (int r = 0; r < 4; ++r) {
      s[r] += __shfl_xor(s[r], off);
      s2[r] += __shfl_xor(s2[r], off);
    }
  float mean[4], rstd[4];
#pragma unroll
  for (int r = 0; r < 4; ++r) {
    mean[r] = s[r] * (1.0f / 256.0f);
    float var = s2[r] * (1.0f / 256.0f) - mean[r] * mean[r];
    rstd[r] = rsqrtf(var + 1e-5f);
  }
#pragma unroll
  for (int fj = 0; fj < 16; ++fj) {
    int col = fj * 16 + fr;
    float gv = gp[col], bev = bep[col];
#pragma unroll
    for (int r = 0; r < 4; ++r) {
      float o = (acc[fj][r] - mean[r]) * rstd[r] * gv + bev;
      xf[(size_t)(rbase + r) * 256 + col] = o;
      xb[(size_t)(rbase + r) * 256 + col] = f2bf(o);
    }
  }
}

// ---------------- MFMA flash attention, bf16 I/O ----------------
template <int MODE>
__global__ __launch_bounds__(512) void mattn_kernel(
    const short* __restrict__ qb, const short* __restrict__ kb, const short* __restrict__ vb,
    short* __restrict__ ob,
    const int* __restrict__ asgn, const int* __restrict__ fullm, const int* __restrict__ padm) {
  __shared__ short Ks[512][40];
  __shared__ short Vt[32][520];
  __shared__ short Pb[8][16][40];
  __shared__ unsigned int mwords[16];
  const int bh = blockIdx.x;
  const int b = (bh >> 3) & 7;
  const size_t base = (size_t)bh * (512 * 32);
  const int tid = threadIdx.x;

#pragma unroll
  for (int r = 0; r < 4; ++r) {
    int i = r * 512 + tid;
    int row = i >> 2, seg = (i & 3) * 8;
    *(bf16x8*)&Ks[row][seg] = *(const bf16x8*)(kb + base + row * 32 + seg);
  }
  {
    int d = tid & 31, g = tid >> 5;
#pragma unroll
    for (int r = 0; r < 8; ++r) {
      int key0 = (r * 16 + g) * 4;
      const short* vp = vb + base + (size_t)key0 * 32 + d;
      unsigned short p0 = (unsigned short)vp[0];
      unsigned short p1 = (unsigned short)vp[32];
      unsigned short p2 = (unsigned short)vp[64];
      unsigned short p3 = (unsigned short)vp[96];
      int lo = ((int)p0) | (((int)p1) << 16);
      int hi = ((int)p2) | (((int)p3) << 16);
      *(int2*)&Vt[d][key0] = make_int2(lo, hi);
    }
  }
  if (tid < 16) {
    unsigned w = 0;
    for (int tl = 0; tl < 32; ++tl) {
      int key = tl * 16 + tid;
      int m = (MODE == 0) ? padm[b * CT + key] : fullm[b * CA + key];
      w |= ((unsigned)(m != 0)) << tl;
    }
    mwords[tid] = w;
  }
  __syncthreads();

  const int wave = tid >> 6, lane = tid & 63;
  const int fr = lane & 15, fs = lane >> 4;
  const int q0 = blockIdx.y * 128 + wave * 16;
  const int q = q0 + fr;

  bf16x8 qf = *(const bf16x8*)(qb + base + (size_t)q * 32 + fs * 8);

  unsigned qmbits = 0;
  if (MODE == 1) {
    int qm = asgn[b * CT + q] | padm[b * CT + q];
    qmbits = qm ? 0xFFFFFFFFu : 0u;
  }
  unsigned mw[4];
#pragma unroll
  for (int g = 0; g < 4; ++g) mw[g] = mwords[4 * fs + g] | qmbits;

  // pass 1: S^T = mfma(K_tile, Q): lane holds S[key = tl*16 + fs*4+reg][q = fr]
  f32x4 s[32];
#pragma unroll
  for (int tl = 0; tl < 32; ++tl) {
    bf16x8 kf = *(bf16x8*)&Ks[tl * 16 + fr][fs * 8];
    f32x4 z = {0.f, 0.f, 0.f, 0.f};
    s[tl] = __builtin_amdgcn_mfma_f32_16x16x32_bf16(kf, qf, z, 0, 0, 0);
  }
  const float sc = 0.17677669529663687f;   // 1/sqrt(32), folded into exp arg
  float mx = -3.0e38f;
#pragma unroll
  for (int tl = 0; tl < 32; ++tl)
#pragma unroll
    for (int g = 0; g < 4; ++g) mx = fmaxf(mx, s[tl][g]);
  mx = fmaxf(mx, __shfl_xor(mx, 16));
  mx = fmaxf(mx, __shfl_xor(mx, 32));
  float sum = 0.f;
#pragma unroll
  for (int tl = 0; tl < 32; ++tl)
#pragma unroll
    for (int g = 0; g < 4; ++g) {
      float e = __expf((s[tl][g] - mx) * sc);
      e = ((mw[g] >> tl) & 1u) ? 0.0f : e;
      s[tl][g] = e;
      sum += e;
    }
  sum += __shfl_xor(sum, 16);
  sum += __shfl_xor(sum, 32);
  float inv = (sum > 0.f) ? (1.0f / sum) : 0.0f;

  // pass 2: O = mfma(P, V^T), unnormalized P; normalize at epilogue
  f32x4 o0 = {0.f, 0.f, 0.f, 0.f}, o1 = {0.f, 0.f, 0.f, 0.f};
#pragma unroll
  for (int c = 0; c < 16; ++c) {
    int w0, w1, w2, w3;
    asm("v_cvt_pk_bf16_f32 %0, %1, %2" : "=v"(w0) : "v"(s[2 * c][0]), "v"(s[2 * c][1]));
    asm("v_cvt_pk_bf16_f32 %0, %1, %2" : "=v"(w1) : "v"(s[2 * c][2]), "v"(s[2 * c][3]));
    asm("v_cvt_pk_bf16_f32 %0, %1, %2" : "=v"(w2) : "v"(s[2 * c + 1][0]), "v"(s[2 * c + 1][1]));
    asm("v_cvt_pk_bf16_f32 %0, %1, %2" : "=v"(w3) : "v"(s[2 * c + 1][2]), "v"(s[2 * c + 1][3]));
    *(int2*)&Pb[wave][fr][4 * fs] = make_int2(w0, w1);
    *(int2*)&Pb[wave][fr][16 + 4 * fs] = make_int2(w2, w3);
    asm volatile("s_waitcnt lgkmcnt(0)" ::: "memory");
    __builtin_amdgcn_sched_barrier(0);
    bf16x8 af = *(bf16x8*)&Pb[wave][fr][8 * fs];
    bf16x8 v0 = *(bf16x8*)&Vt[fr][32 * c + 8 * fs];
    bf16x8 v1 = *(bf16x8*)&Vt[16 + fr][32 * c + 8 * fs];
    o0 = __builtin_amdgcn_mfma_f32_16x16x32_bf16(af, v0, o0, 0, 0, 0);
    o1 = __builtin_amdgcn_mfma_f32_16x16x32_bf16(af, v1, o1, 0, 0, 0);
  }
#pragma unroll
  for (int g = 0; g < 4; ++g) {
    float iv = __shfl(inv, fs * 4 + g);
    int qq = q0 + fs * 4 + g;
    ob[base + (size_t)qq * 32 + fr] = f2bf(o0[g] * iv);
    ob[base + (size_t)qq * 32 + 16 + fr] = f2bf(o1[g] * iv);
  }
}

// ---------------- final: 8*tanh(scores/16), mask, softmax over a, write transposed ----------------
__global__ void final_kernel(const float* __restrict__ scores,
                             const int* __restrict__ asgn, const int* __restrict__ fullm,
                             const int* __restrict__ padm, float* __restrict__ out) {
  int row = blockIdx.x;   // b*512 + t
  int b = row >> 9, t = row & 511;
  int lane = threadIdx.x;
  int qm = asgn[row] | padm[row];
  const float* sp = scores + (size_t)row * 512;
  float v[8];
  int mk[8];
#pragma unroll
  for (int m = 0; m < 8; ++m) {
    int a = lane + (m << 6);
    float val = 8.0f * tanhf(sp[a] * (1.0f / 16.0f));
    int masked = qm | fullm[b * CA + a];
    mk[m] = masked;
    v[m] = masked ? NEGV : val;
  }
  float mx = v[0];
#pragma unroll
  for (int m = 1; m < 8; ++m) mx = fmaxf(mx, v[m]);
#pragma unroll
  for (int off = 32; off >= 1; off >>= 1) mx = fmaxf(mx, __shfl_xor(mx, off));
  float sum = 0.f, e[8];
#pragma unroll
  for (int m = 0; m < 8; ++m) { e[m] = __expf(v[m] - mx); sum += e[m]; }
#pragma unroll
  for (int off = 32; off >= 1; off >>= 1) sum += __shfl_xor(sum, off);
  float inv = 1.0f / sum;
#pragma unroll
  for (int m = 0; m < 8; ++m) {
    int a = lane + (m << 6);
    float p = mk[m] ? 0.0f : e[m] * inv;
    out[(size_t)b * (CA * CT) + (size_t)a * CT + t] = p;   // (B,A,T)
  }
}

extern "C" void kernel_launch(void* const* d_in, const int* in_sizes, int n_in,
                              void* d_out, int out_size, void* d_ws, size_t ws_size,
                              hipStream_t stream) {
  const int* tasks = (const int*)d_in[0];
  const int* agents = (const int*)d_in[1];
  const int* indices = (const int*)d_in[2];
  const float* emb_t = (const float*)d_in[3];
  const float* emb_t_wo = (const float*)d_in[4];
  const float* emb_t_bo = (const float*)d_in[5];
  const float* emb_a = (const float*)d_in[6];
  const float* emb_a_wo = (const float*)d_in[7];
  const float* emb_a_bo = (const float*)d_in[8];
  const float* de_wq = (const float*)d_in[33];
  const float* de_wk = (const float*)d_in[34];
  const float* de_wv = (const float*)d_in[35];
  const float* de_wo = (const float*)d_in[36];
  const float* de_w1 = (const float*)d_in[37];
  const float* de_b1 = (const float*)d_in[38];
  const float* de_w2 = (const float*)d_in[39];
  const float* de_b2 = (const float*)d_in[40];
  const float* de_g1 = (const float*)d_in[41];
  const float* de_be1 = (const float*)d_in[42];
  const float* de_g2 = (const float*)d_in[43];
  const float* de_be2 = (const float*)d_in[44];
  const float* do_wq = (const float*)d_in[45];
  const float* do_wk = (const float*)d_in[46];

  float* ws = (float*)d_ws;
  float* ht = ws + 0;                      // [0,1M) f32 4096x256
  float* ha = ws + 1048576;                // [1M,2M)
  short* htb = (short*)(ws + 2097152);     // [2M,2.5M) bf16 shadow
  short* hab = (short*)(ws + 2621440);     // [2.5M,3M)
  short* qall = (short*)(ws + 3145728);    // [3M,4M)   2M shorts (both encoders)
  short* kall = (short*)(ws + 4194304);    // [4M,5M)
  short* vall = (short*)(ws + 5242880);    // [5M,6M)
  short* t1b = (short*)(ws + 6291456);     // [6M,10M)  8M shorts (attn-out / FFN mid x2)
  float* scores = ws + 6291456;            // alias t1b (used only after t1b dead)
  short* wT = (short*)(ws + 12582912);     // [12M,~14.75M) transposed bf16 weights
  int* asgn = (int*)(ws + 15400000);
  int* fullm = asgn + 4096;
  int* padm = asgn + 8192;

  // ---- build weight-transpose table ----
  TArgs ta;
  int idx = 0, tb = 0;
  size_t doff = 0;
  short* Wp[46];
  auto addw = [&](const float* s, int K, int N) {
    Wp[idx] = wT + doff;
    ta.d[idx] = {s, wT + doff, K, N, tb};
    tb += (K >> 6) * (N >> 6);
    doff += (size_t)K * N;
    ++idx;
  };
  addw(emb_t_wo, 256, 256);   // 0
  addw(emb_a_wo, 256, 256);   // 1
  for (int enc = 0; enc < 2; ++enc) {
    int pb = enc ? 21 : 9;
    const float* wq = (const float*)d_in[pb + 0];
    const float* wk = (const float*)d_in[pb + 1];
    const float* wv = (const float*)d_in[pb + 2];
    const float* wo = (const float*)d_in[pb + 3];
    const float* w1 = (const float*)d_in[pb + 4];
    const float* w2 = (const float*)d_in[pb + 6];
    for (int l = 0; l < 3; ++l) {
      addw(wq + l * 65536, 256, 256);
      addw(wk + l * 65536, 256, 256);
      addw(wv + l * 65536, 256, 256);
      addw(wo + l * 65536, 256, 256);
    }
    for (int l = 0; l < 3; ++l) addw(w1 + l * 262144, 256, 1024);
    for (int l = 0; l < 3; ++l) addw(w2 + l * 262144, 1024, 256);
  }
  addw(de_wq, 256, 256);      // 38
  addw(de_wk, 256, 256);      // 39
  addw(de_wv, 256, 256);      // 40
  addw(de_wo, 256, 256);      // 41
  addw(de_w1, 256, 512);      // 42
  addw(de_w2, 512, 256);      // 43
  addw(do_wq, 256, 256);      // 44
  addw(do_wk, 256, 256);      // 45
  ta.nd = idx;

  mask_prep_kernel<<<16, 256, 0, stream>>>(tasks, indices, asgn, fullm, padm);
  mask_assign_kernel<<<128, 256, 0, stream>>>(indices, asgn);
  trans_kernel<<<tb, 256, 0, stream>>>(ta);

  GArgs ga{};
  LArgs la{};

  // embeddings (staged bf16 into t1b halves), then projection+bias into ht/ha (+shadows)
  embed2_kernel<<<8192, 64, 0, stream>>>(tasks, agents, emb_t, emb_a, t1b);
  ga.A[0] = t1b;            ga.Bm[0] = Wp[0]; ga.bias[0] = emb_t_bo; ga.Cf[0] = ht; ga.Cb[0] = htb;
  ga.A[1] = t1b + 1048576;  ga.Bm[1] = Wp[1]; ga.bias[1] = emb_a_bo; ga.Cf[1] = ha; ga.Cb[1] = hab;
  ga.Ndim = 256; ga.Kdim = 256;
  mgemm_kernel<2, true, false><<<dim3(32, 4, 2), 256, 0, stream>>>(ga);

  const float* b1t = (const float*)d_in[14];
  const float* b2t = (const float*)d_in[16];
  const float* g1t = (const float*)d_in[17];
  const float* be1t = (const float*)d_in[18];
  const float* g2t = (const float*)d_in[19];
  const float* be2t = (const float*)d_in[20];
  const float* b1a = (const float*)d_in[26];
  const float* b2a = (const float*)d_in[28];
  const float* g1a = (const float*)d_in[29];
  const float* be1a = (const float*)d_in[30];
  const float* g2a = (const float*)d_in[31];
  const float* be2a = (const float*)d_in[32];

  // both encoders together, 3 layers
  for (int l = 0; l < 3; ++l) {
    // QKV x2 encoders (z=6)
    for (int j = 0; j < 3; ++j) {
      ga.A[j] = htb;     ga.Bm[j] = Wp[2 + l * 4 + j];
      ga.A[3 + j] = hab; ga.Bm[3 + j] = Wp[20 + l * 4 + j];
    }
    short* outs[6] = {qall, kall, vall, qall + 1048576, kall + 1048576, vall + 1048576};
    for (int j = 0; j < 6; ++j) ga.Cb[j] = outs[j];
    ga.Ndim = 256; ga.Kdim = 256;
    mgemm_kernel<1, false, false><<<dim3(32, 4, 6), 256, 0, stream>>>(ga);
    // attention, 128 head-slots (64 enc-t + 64 enc-a)
    mattn_kernel<0><<<dim3(128, 4, 1), 512, 0, stream>>>(qall, kall, vall, t1b,
                                                         asgn, fullm, padm);
    // wo x2 + residual + LN1 (fused)
    la.A[0] = t1b;           la.Bm[0] = Wp[2 + l * 4 + 3];
    la.A[1] = t1b + 1048576; la.Bm[1] = Wp[20 + l * 4 + 3];
    la.x[0] = ht; la.xb[0] = htb; la.g[0] = g1t + l * 256; la.be[0] = be1t + l * 256;
    la.x[1] = ha; la.xb[1] = hab; la.g[1] = g1a + l * 256; la.be[1] = be1a + l * 256;
    la.Kdim = 256;
    mgemmln_kernel<false><<<dim3(64, 1, 2), 256, 0, stream>>>(la);
    // FFN1 x2 (relu+bias, bf16 out)
    ga.A[0] = htb; ga.Bm[0] = Wp[14 + l]; ga.bias[0] = b1t + l * 1024; ga.Cb[0] = t1b;
    ga.A[1] = hab; ga.Bm[1] = Wp[32 + l]; ga.bias[1] = b1a + l * 1024; ga.Cb[1] = t1b + 4194304;
    ga.Ndim = 1024; ga.Kdim = 256;
    mgemm_kernel<1, true, true><<<dim3(32, 16, 2), 256, 0, stream>>>(ga);
    // FFN2 x2 + bias + residual + LN2 (fused)
    la.A[0] = t1b;           la.Bm[0] = Wp[17 + l]; la.bias[0] = b2t + l * 256;
    la.A[1] = t1b + 4194304; la.Bm[1] = Wp[35 + l]; la.bias[1] = b2a + l * 256;
    la.x[0] = ht; la.xb[0] = htb; la.g[0] = g2t + l * 256; la.be[0] = be2t + l * 256;
    la.x[1] = ha; la.xb[1] = hab; la.g[1] = g2a + l * 256; la.be[1] = be2a + l * 256;
    la.Kdim = 1024;
    mgemmln_kernel<true><<<dim3(64, 1, 2), 256, 0, stream>>>(la);
  }

  // decoder cross-attention block (ht := h)
  ga.A[0] = htb; ga.Bm[0] = Wp[38]; ga.Cb[0] = qall;
  ga.A[1] = hab; ga.Bm[1] = Wp[39]; ga.Cb[1] = kall;
  ga.A[2] = hab; ga.Bm[2] = Wp[40]; ga.Cb[2] = vall;
  ga.Ndim = 256; ga.Kdim = 256;
  mgemm_kernel<1, false, false><<<dim3(32, 4, 3), 256, 0, stream>>>(ga);
  mattn_kernel<1><<<dim3(64, 4, 1), 512, 0, stream>>>(qall, kall, vall, t1b,
                                                      asgn, fullm, padm);
  la.A[0] = t1b; la.Bm[0] = Wp[41];
  la.x[0] = ht; la.xb[0] = htb; la.g[0] = de_g1; la.be[0] = de_be1;
  la.Kdim = 256;
  mgemmln_kernel<false><<<dim3(64, 1, 1), 256, 0, stream>>>(la);
  ga.A[0] = htb; ga.Bm[0] = Wp[42]; ga.bias[0] = de_b1; ga.Cb[0] = t1b;
  ga.Ndim = 512; ga.Kdim = 256;
  mgemm_kernel<1, true, true><<<dim3(32, 8, 1), 256, 0, stream>>>(ga);
  la.A[0] = t1b; la.Bm[0] = Wp[43]; la.bias[0] = de_b2;
  la.x[0] = ht; la.xb[0] = htb; la.g[0] = de_g2; la.be[0] = de_be2;
  la.Kdim = 512;
  mgemmln_kernel<true><<<dim3(64, 1, 1), 256, 0, stream>>>(la);

  // final scores + softmax + transpose
  ga.A[0] = htb; ga.Bm[0] = Wp[44]; ga.Cb[0] = qall;
  ga.A[1] = hab; ga.Bm[1] = Wp[45]; ga.Cb[1] = kall;
  ga.Ndim = 256; ga.Kdim = 256;
  mgemm_kernel<1, false, false><<<dim3(32, 4, 2), 256, 0, stream>>>(ga);
  for (int b = 0; b < 8; ++b) {
    ga.A[b] = qall + (size_t)b * 131072;
    ga.Bm[b] = kall + (size_t)b * 131072;
    ga.Cf[b] = scores + (size_t)b * 262144;
  }
  ga.Ndim = 512; ga.Kdim = 256;
  mgemm_kernel<0, false, false><<<dim3(4, 8, 8), 256, 0, stream>>>(ga);
  final_kernel<<<4096, 64, 0, stream>>>(scores, asgn, fullm, padm, (float*)d_out);
}